// Round 9
// baseline (119.509 us; speedup 1.0000x reference)
//
#include <hip/hip_runtime.h>
#include <stdint.h>

#define NROWS 8192
#define DD 128
#define EPS 1e-8f
#define LOG2E 1.4426950408889634f

// main kernel tiling
#define SPLIT 16       // column splits -> 1024 blocks -> 4 blocks/CU
#define RPB 128        // rows per block (4 waves x 2 strips x 16 rows)
#define TCOLS 64       // cols per LDS tile
#define TBYTES (TCOLS * 256)          // 16 KB per tile buffer
#define NT ((NROWS / SPLIT) / TCOLS)  // 8 tiles per block
#define NORM_BLOCKS (NROWS / 4)
#define PACK_BLOCKS 3200   // 100 classes * 128 u64-words / 4 waves

typedef __bf16 bf16x8 __attribute__((ext_vector_type(8)));
typedef float f32x4 __attribute__((ext_vector_type(4)));
typedef __attribute__((address_space(1))) unsigned int as1_u32;
typedef __attribute__((address_space(3))) unsigned int as3_u32;

__device__ __forceinline__ unsigned int f2bf(float f) {
  union { float f; unsigned int u; } v; v.f = f;
  unsigned int u = v.u;
  return (u + 0x7fffu + ((u >> 16) & 1u)) >> 16;
}
__device__ __forceinline__ float bf2f(unsigned int b) {
  union { unsigned int u; float f; } v; v.u = b << 16;
  return v.f;
}

// Kernel 1 (blocks < NORM_BLOCKS): per-row normalize.
//   xnA  = bf16(x/||x|| * log2e/T)  (A operand pre-scaled: e = exp2(acc))
//   xnBt = bf16(x/||x||) in MFMA B-FRAGMENT ORDER:
//          chunk(row j, kstep, q) at (j>>4)*4096 + kstep*1024 + q*256 + (j&15)*16
//          (4 KB per 16 rows, contiguous in exactly lane*16 order ->
//           global_load_lds-stageable and ds_read_b128-readable)
//   p = exp2(cos(x,proxy)*log2e/T)  [margin cancels in num/den ratio]
//   e_self = exp2(<xnA_bf16, xnB_bf16>)  (MFMA diagonal, subtracted in loss)
//   mii = negmask[label_i][i]; zero tot/msk/out.
// Kernel 1 (blocks >= NORM_BLOCKS): ballot-pack negmask into u32 bit-words:
//   packed[class*256 + j/32] bit (j&31) = (negmask[class][j] != 0)
__global__ __launch_bounds__(256) void norm_kernel(
    const float* __restrict__ x, const float* __restrict__ pr,
    const float* __restrict__ nm, const int* __restrict__ lb,
    const float* __restrict__ tptr,
    unsigned short* __restrict__ xnA, unsigned char* __restrict__ xnBt,
    float* __restrict__ p, float* __restrict__ eself, float* __restrict__ mii,
    float* __restrict__ tot, float* __restrict__ msk,
    unsigned int* __restrict__ packed, float* __restrict__ out)
{
  int wave = threadIdx.x >> 6, lane = threadIdx.x & 63;
  int bx = blockIdx.x;

  if (bx >= NORM_BLOCKS) {
    // ---- mask pack branch ----
    int widx = (bx - NORM_BLOCKS) * 4 + wave;   // 0..12799
    int cls = widx >> 7;                        // 0..99
    int w64 = widx & 127;                       // u64-word within class
    float v = nm[(size_t)cls * NROWS + w64 * 64 + lane];
    unsigned long long b = __ballot(v != 0.0f);
    if (lane == 0) {
      packed[cls * 256 + w64 * 2] = (unsigned int)b;
      packed[cls * 256 + w64 * 2 + 1] = (unsigned int)(b >> 32);
    }
    return;
  }

  int row = bx * 4 + wave;
  float2 xv = ((const float2*)(x + (size_t)row * DD))[lane];
  float2 pv = ((const float2*)(pr + (size_t)row * DD))[lane];
  float sx = xv.x * xv.x + xv.y * xv.y;
  float sp = pv.x * pv.x + pv.y * pv.y;
  float dp = xv.x * pv.x + xv.y * pv.y;
  #pragma unroll
  for (int m = 1; m < 64; m <<= 1) {
    sx += __shfl_xor(sx, m);
    sp += __shfl_xor(sp, m);
    dp += __shfl_xor(dp, m);
  }
  float inx = 1.f / fmaxf(sqrtf(sx), EPS);
  float inp = 1.f / fmaxf(sqrtf(sp), EPS);
  float s1 = LOG2E / tptr[0];

  unsigned int a0 = f2bf(xv.x * inx * s1), a1 = f2bf(xv.y * inx * s1);
  unsigned int b0 = f2bf(xv.x * inx),      b1 = f2bf(xv.y * inx);
  ((unsigned int*)(xnA + (size_t)row * DD))[lane] = a0 | (a1 << 16);

  // fragment-order B store: lane holds elements 2*lane, 2*lane+1
  //   = kstep*32 + q*8 + pos*2 with kstep=lane>>4, q=(lane>>2)&3, pos=lane&3
  {
    int kstep = lane >> 4, qq = (lane >> 2) & 3, pos = lane & 3;
    unsigned int dst = ((unsigned int)(row >> 4)) * 4096u + kstep * 1024u +
                       qq * 256u + (row & 15) * 16u + pos * 4u;
    *(unsigned int*)(xnBt + dst) = b0 | (b1 << 16);
  }

  // self-sim with the SAME rounded values the MFMA will see
  float ss = bf2f(a0) * bf2f(b0) + bf2f(a1) * bf2f(b1);
  #pragma unroll
  for (int m = 1; m < 64; m <<= 1) ss += __shfl_xor(ss, m);

  if (lane == 0) {
    p[row] = __builtin_amdgcn_exp2f(dp * inx * inp * s1);
    eself[row] = __builtin_amdgcn_exp2f(ss);
    mii[row] = nm[(size_t)lb[row] * NROWS + row];
    tot[row] = 0.f;
    msk[row] = 0.f;
    if (row == 0) out[0] = 0.f;
  }
}

// Kernel 2: fused sim-GEMM + exp + masked/total row-sum accumulation.
// Block = 256 threads = 4 waves; each wave owns 2 strips of 16 rows (RPB=128).
// Grid: (NROWS/RPB, SPLIT) = 1024 blocks. B tiles (64 cols = 16 KB) staged
// COOPERATIVELY via async global_load_lds (zero staging VGPRs, 4x less
// global traffic than per-wave loads), double-buffered LDS, ONE barrier
// per tile: prefetch issued at tile top has the whole tile compute to land
// before the pre-barrier vmcnt drain (m97 structure). ds_read_b128 at
// lane*16 -> linear, conflict-free. Masks bit-packed, uint2 per 64 cols.
__global__ __launch_bounds__(256, 4) void main_kernel(
    const unsigned short* __restrict__ xnA_u, const unsigned char* __restrict__ xnBt,
    const unsigned int* __restrict__ packed, const int* __restrict__ labels,
    float* __restrict__ tot, float* __restrict__ msk)
{
  __shared__ unsigned char lds[2][TBYTES];   // 2 x 16 KB
  int tid = threadIdx.x;
  int wave = tid >> 6, lane = tid & 63;
  int q = lane >> 4, c = lane & 15;
  int rb0 = blockIdx.x * RPB + wave * 16;  // strip 0 row base
  int rb1 = rb0 + 64;                      // strip 1 row base

  const bf16x8* xnvA = (const bf16x8*)xnA_u;

  // A fragments (held in registers for the whole column loop)
  // layout: m = lane&15, k = (lane>>4)*8 + j  per 32-wide K step
  bf16x8 a0[4], a1[4];
  {
    const bf16x8* b = xnvA + (size_t)(rb0 + c) * (DD / 8) + q;
    a0[0] = b[0]; a0[1] = b[4]; a0[2] = b[8]; a0[3] = b[12];
  }
  {
    const bf16x8* b = xnvA + (size_t)(rb1 + c) * (DD / 8) + q;
    a1[0] = b[0]; a1[1] = b[4]; a1[2] = b[8]; a1[3] = b[12];
  }

  int jb = blockIdx.y * (NROWS / SPLIT);

  // Epilogue rows for this lane: row_local = q*4 + k, col = s*16 + c
  int r0[4], r1[4];
  unsigned int offP0[4], offP1[4];        // packed-mask word offsets
  #pragma unroll
  for (int k = 0; k < 4; k++) {
    r0[k] = rb0 + q * 4 + k;
    r1[k] = rb1 + q * 4 + k;
    offP0[k] = (unsigned int)labels[r0[k]] * 256u + (unsigned int)(jb >> 5);
    offP1[k] = (unsigned int)labels[r1[k]] * 256u + (unsigned int)(jb >> 5);
  }
  float t0[4] = {0, 0, 0, 0}, m0[4] = {0, 0, 0, 0};
  float t1[4] = {0, 0, 0, 0}, m1[4] = {0, 0, 0, 0};

  // async staging: wave stages its 4 KB quarter of the 16 KB tile,
  // 4 x global_load_lds (1 KB each: wave-uniform LDS base + lane*16)
  const unsigned char* gW = xnBt + (size_t)(jb >> 4) * 4096 +
                            (unsigned int)(wave * 4096 + lane * 16);
  unsigned int ldsW = (unsigned int)(wave * 4096);

  auto stage = [&](int t, int b) {
    const unsigned char* g = gW + (unsigned int)t * (unsigned int)TBYTES;
    unsigned char* d = lds[b] + ldsW;
    #pragma unroll
    for (int i = 0; i < 4; i++) {
      __builtin_amdgcn_global_load_lds((const as1_u32*)(g + i * 1024),
                                       (as3_u32*)(d + i * 1024), 16, 0, 0);
    }
  };

  stage(0, 0);
  __syncthreads();

  for (int t = 0; t < NT; t++) {
    // issue next tile's async staging into the other buffer
    if (t + 1 < NT) stage(t + 1, (t + 1) & 1);

    // mask words for this tile's 64 cols (uint2 per strip-row), L1-resident
    uint2 wA0[4], wA1[4];
    #pragma unroll
    for (int k = 0; k < 4; k++) {
      wA0[k] = *(const uint2*)&packed[offP0[k] + 2 * t];
      wA1[k] = *(const uint2*)&packed[offP1[k] + 2 * t];
    }

    const unsigned char* buf = lds[t & 1] + (unsigned int)(lane * 16);
    #pragma unroll
    for (int s = 0; s < 4; s++) {
      const unsigned char* sb = buf + s * 4096;
      bf16x8 b0 = *(const bf16x8*)(sb);
      bf16x8 b1 = *(const bf16x8*)(sb + 1024);
      bf16x8 b2 = *(const bf16x8*)(sb + 2048);
      bf16x8 b3 = *(const bf16x8*)(sb + 3072);

      f32x4 acc0 = {0, 0, 0, 0};
      f32x4 acc1 = {0, 0, 0, 0};
      acc0 = __builtin_amdgcn_mfma_f32_16x16x32_bf16(a0[0], b0, acc0, 0, 0, 0);
      acc1 = __builtin_amdgcn_mfma_f32_16x16x32_bf16(a1[0], b0, acc1, 0, 0, 0);
      acc0 = __builtin_amdgcn_mfma_f32_16x16x32_bf16(a0[1], b1, acc0, 0, 0, 0);
      acc1 = __builtin_amdgcn_mfma_f32_16x16x32_bf16(a1[1], b1, acc1, 0, 0, 0);
      acc0 = __builtin_amdgcn_mfma_f32_16x16x32_bf16(a0[2], b2, acc0, 0, 0, 0);
      acc1 = __builtin_amdgcn_mfma_f32_16x16x32_bf16(a1[2], b2, acc1, 0, 0, 0);
      acc0 = __builtin_amdgcn_mfma_f32_16x16x32_bf16(a0[3], b3, acc0, 0, 0, 0);
      acc1 = __builtin_amdgcn_mfma_f32_16x16x32_bf16(a1[3], b3, acc1, 0, 0, 0);

      int pos = (s & 1) * 16 + c;   // bit within the selected u32 (s<2 -> .x)
      #pragma unroll
      for (int k = 0; k < 4; k++) {
        unsigned int w = (s < 2) ? wA0[k].x : wA0[k].y;
        float e = __builtin_amdgcn_exp2f(acc0[k]);
        t0[k] += e;
        m0[k] = fmaf(e, (float)((w >> pos) & 1u), m0[k]);
      }
      #pragma unroll
      for (int k = 0; k < 4; k++) {
        unsigned int w = (s < 2) ? wA1[k].x : wA1[k].y;
        float e = __builtin_amdgcn_exp2f(acc1[k]);
        t1[k] += e;
        m1[k] = fmaf(e, (float)((w >> pos) & 1u), m1[k]);
      }
    }
    // one barrier: drains this tile's compute AND next tile's staging loads
    __syncthreads();
  }

  // Reduce across the 16 lanes (c) sharing each q group.
  #pragma unroll
  for (int sh = 1; sh < 16; sh <<= 1) {
    #pragma unroll
    for (int k = 0; k < 4; k++) {
      t0[k] += __shfl_xor(t0[k], sh);
      m0[k] += __shfl_xor(m0[k], sh);
      t1[k] += __shfl_xor(t1[k], sh);
      m1[k] += __shfl_xor(m1[k], sh);
    }
  }
  if (c == 0) {
    #pragma unroll
    for (int k = 0; k < 4; k++) {
      atomicAdd(&tot[r0[k]], t0[k]);
      atomicAdd(&msk[r0[k]], m0[k]);
      atomicAdd(&tot[r1[k]], t1[k]);
      atomicAdd(&msk[r1[k]], m1[k]);
    }
  }
}

// Kernel 3: loss = mean(log(p+tot') - log(p+msk')), diagonal subtracted here.
__global__ __launch_bounds__(256) void loss_kernel(
    const float* __restrict__ p, const float* __restrict__ tot,
    const float* __restrict__ msk, const float* __restrict__ eself,
    const float* __restrict__ mii, float* __restrict__ out)
{
  __shared__ float sd[4];
  int r = blockIdx.x * 256 + threadIdx.x;
  float pi = p[r];
  float es = eself[r];
  float t = tot[r] - es;                 // remove diagonal from total sum
  float m = msk[r] - es * mii[r];        // remove diagonal from masked sum
  float v = __builtin_amdgcn_logf(pi + t) - __builtin_amdgcn_logf(pi + m);
  float s = v * (1.0f / (LOG2E * (float)NROWS));
  #pragma unroll
  for (int sh = 1; sh < 64; sh <<= 1) s += __shfl_xor(s, sh);
  int wave = threadIdx.x >> 6, lane = threadIdx.x & 63;
  if (lane == 0) sd[wave] = s;
  __syncthreads();
  if (threadIdx.x == 0) atomicAdd(out, sd[0] + sd[1] + sd[2] + sd[3]);
}

extern "C" void kernel_launch(void* const* d_in, const int* in_sizes, int n_in,
                              void* d_out, int out_size, void* d_ws, size_t ws_size,
                              hipStream_t stream) {
  const float* x  = (const float*)d_in[0];   // inst_embed [N,D]
  const float* pr = (const float*)d_in[1];   // proxy [N,D]
  const float* nm = (const float*)d_in[2];   // negative_mask [100,N]
  const int*   lb = (const int*)d_in[3];     // labels [N]
  const float* tp = (const float*)d_in[4];   // temperature
  // margin (d_in[5]) cancels algebraically in numerator/denominator

  char* ws = (char*)d_ws;
  unsigned short* xnA = (unsigned short*)ws;                        // 2 MB
  unsigned char* xnBt = (unsigned char*)(xnA + (size_t)NROWS * DD); // 2 MB
  float* p     = (float*)(xnBt + (size_t)NROWS * DD * 2);
  float* tot   = p + NROWS;
  float* msk   = tot + NROWS;
  float* eself = msk + NROWS;
  float* miiv  = eself + NROWS;
  unsigned int* packed = (unsigned int*)(miiv + NROWS);             // 102.4 KB
  float* out = (float*)d_out;

  norm_kernel<<<NORM_BLOCKS + PACK_BLOCKS, 256, 0, stream>>>(
      x, pr, nm, lb, tp, xnA, xnBt, p, eself, miiv, tot, msk, packed, out);
  main_kernel<<<dim3(NROWS / RPB, SPLIT), 256, 0, stream>>>(xnA, xnBt, packed,
                                                            lb, tot, msk);
  loss_kernel<<<NROWS / 256, 256, 0, stream>>>(p, tot, msk, eself, miiv, out);
}

// Round 10
// 106.245 us; speedup vs baseline: 1.1248x; 1.1248x over previous
//
#include <hip/hip_runtime.h>
#include <stdint.h>

#define NROWS 8192
#define DD 128
#define EPS 1e-8f
#define LOG2E 1.4426950408889634f

// main kernel tiling
#define SPLIT 16       // column splits; grid = (128, 16) = 2048 blocks -> 8/CU
#define RPB 64         // rows per block (4 waves x 1 strip x 16 rows)
#define CPT 32         // cols per LDS tile (2 uint4/thread staging - no spill)
#define LDS_COL 272    // bytes per staged col (256+16 pad; bank group (c+q)%8)
#define NT ((NROWS / SPLIT) / CPT)   // 16 tiles per block
#define NORM_BLOCKS (NROWS / 4)
#define PACK_BLOCKS 3200   // 100 classes * 128 u64-words / 4 waves

typedef __bf16 bf16x8 __attribute__((ext_vector_type(8)));
typedef float f32x4 __attribute__((ext_vector_type(4)));

__device__ __forceinline__ unsigned int f2bf(float f) {
  union { float f; unsigned int u; } v; v.f = f;
  unsigned int u = v.u;
  return (u + 0x7fffu + ((u >> 16) & 1u)) >> 16;
}
__device__ __forceinline__ float bf2f(unsigned int b) {
  union { unsigned int u; float f; } v; v.u = b << 16;
  return v.f;
}

// Kernel 1 (blocks < NORM_BLOCKS): per-row normalize.
//   xnA = bf16(x/||x|| * log2e/T)  (A operand pre-scaled: e = exp2(acc))
//   xnB = bf16(x/||x||)            (B operand)
//   p = exp2(cos(x,proxy)*log2e/T)  [margin cancels in num/den ratio]
//   e_self = exp2(<xnA_bf16, xnB_bf16>)  (MFMA diagonal, subtracted in loss)
//   mii = negmask[label_i][i]; zero tot/msk/out.
// Kernel 1 (blocks >= NORM_BLOCKS): ballot-pack negmask into u32 bit-words:
//   packed[class*256 + j/32] bit (j&31) = (negmask[class][j] != 0)
__global__ __launch_bounds__(256) void norm_kernel(
    const float* __restrict__ x, const float* __restrict__ pr,
    const float* __restrict__ nm, const int* __restrict__ lb,
    const float* __restrict__ tptr,
    unsigned short* __restrict__ xnA, unsigned short* __restrict__ xnB,
    float* __restrict__ p, float* __restrict__ eself, float* __restrict__ mii,
    float* __restrict__ tot, float* __restrict__ msk,
    unsigned int* __restrict__ packed, float* __restrict__ out)
{
  int wave = threadIdx.x >> 6, lane = threadIdx.x & 63;
  int bx = blockIdx.x;

  if (bx >= NORM_BLOCKS) {
    // ---- mask pack branch ----
    int widx = (bx - NORM_BLOCKS) * 4 + wave;   // 0..12799
    int cls = widx >> 7;                        // 0..99
    int w64 = widx & 127;                       // u64-word within class
    float v = nm[(size_t)cls * NROWS + w64 * 64 + lane];
    unsigned long long b = __ballot(v != 0.0f);
    if (lane == 0) {
      packed[cls * 256 + w64 * 2] = (unsigned int)b;
      packed[cls * 256 + w64 * 2 + 1] = (unsigned int)(b >> 32);
    }
    return;
  }

  int row = bx * 4 + wave;
  float2 xv = ((const float2*)(x + (size_t)row * DD))[lane];
  float2 pv = ((const float2*)(pr + (size_t)row * DD))[lane];
  float sx = xv.x * xv.x + xv.y * xv.y;
  float sp = pv.x * pv.x + pv.y * pv.y;
  float dp = xv.x * pv.x + xv.y * pv.y;
  #pragma unroll
  for (int m = 1; m < 64; m <<= 1) {
    sx += __shfl_xor(sx, m);
    sp += __shfl_xor(sp, m);
    dp += __shfl_xor(dp, m);
  }
  float inx = 1.f / fmaxf(sqrtf(sx), EPS);
  float inp = 1.f / fmaxf(sqrtf(sp), EPS);
  float s1 = LOG2E / tptr[0];

  unsigned int a0 = f2bf(xv.x * inx * s1), a1 = f2bf(xv.y * inx * s1);
  unsigned int b0 = f2bf(xv.x * inx),      b1 = f2bf(xv.y * inx);
  ((unsigned int*)(xnA + (size_t)row * DD))[lane] = a0 | (a1 << 16);
  ((unsigned int*)(xnB + (size_t)row * DD))[lane] = b0 | (b1 << 16);

  // self-sim with the SAME rounded values the MFMA will see
  float ss = bf2f(a0) * bf2f(b0) + bf2f(a1) * bf2f(b1);
  #pragma unroll
  for (int m = 1; m < 64; m <<= 1) ss += __shfl_xor(ss, m);

  if (lane == 0) {
    p[row] = __builtin_amdgcn_exp2f(dp * inx * inp * s1);
    eself[row] = __builtin_amdgcn_exp2f(ss);
    mii[row] = nm[(size_t)lb[row] * NROWS + row];
    tot[row] = 0.f;
    msk[row] = 0.f;
    if (row == 0) out[0] = 0.f;
  }
}

// Kernel 2: fused sim-GEMM + exp + masked/total row-sum accumulation.
// Block = 256 threads = 4 waves; each wave owns ONE strip of 16 rows
// (RPB=64) -> live regs ~40 (a-frags 16, accums 8, offP 4) — far below the
// 64-VGPR wall that spilled R4/R9. Grid (NROWS/64, SPLIT) = 2048 blocks =
// 8 blocks/CU = 32 waves/CU for stall hiding. B tiles (CPT=32, 8.5 KB)
// staged via 2xuint4/thread into DOUBLE-BUFFERED LDS, one barrier/tile.
__global__ __launch_bounds__(256, 4) void main_kernel(
    const unsigned short* __restrict__ xnA_u, const unsigned short* __restrict__ xnB_u,
    const unsigned int* __restrict__ packed, const int* __restrict__ labels,
    float* __restrict__ tot, float* __restrict__ msk)
{
  __shared__ unsigned char lds[2][CPT * LDS_COL];   // 2 x 8704 B
  int tid = threadIdx.x;
  int wave = tid >> 6, lane = tid & 63;
  int q = lane >> 4, c = lane & 15;
  int rb = blockIdx.x * RPB + wave * 16;   // this wave's 16-row strip

  const bf16x8* xnvA = (const bf16x8*)xnA_u;

  // A fragments (held in registers for the whole column loop)
  // layout: m = lane&15, k = (lane>>4)*8 + j  per 32-wide K step
  bf16x8 a0[4];
  {
    const bf16x8* b = xnvA + (size_t)(rb + c) * (DD / 8) + q;
    a0[0] = b[0]; a0[1] = b[4]; a0[2] = b[8]; a0[3] = b[12];
  }

  int jb = blockIdx.y * (NROWS / SPLIT);

  // Epilogue rows for this lane: row_local = q*4 + k, col = s*16 + c
  unsigned int offP0[4];                  // packed-mask word offsets
  #pragma unroll
  for (int k = 0; k < 4; k++)
    offP0[k] = (unsigned int)labels[rb + q * 4 + k] * 256u +
               (unsigned int)(jb >> 5);
  float t0[4] = {0, 0, 0, 0}, m0[4] = {0, 0, 0, 0};

  // staging: thread t loads/writes 2x 16B: cols scol, scol+16, chunk schunk
  int scol = tid >> 4, schunk = tid & 15;
  const char* gB = (const char*)xnB_u;
  const char* gbase = gB + (size_t)(jb + scol) * 256 + schunk * 16;
  unsigned int ldsoff = (unsigned int)(scol * LDS_COL + schunk * 16);

  // prefetch + stage tile 0 into buffer 0
  uint4 g0 = *(const uint4*)(gbase);
  uint4 g1 = *(const uint4*)(gbase + 16 * 256);
  *(uint4*)(lds[0] + ldsoff)                = g0;
  *(uint4*)(lds[0] + ldsoff + 16 * LDS_COL) = g1;
  __syncthreads();

  for (int t = 0; t < NT; t++) {
    // this tile's mask words (L2-resident; latency covered by MFMA chain)
    unsigned int wc0[4];
    #pragma unroll
    for (int k = 0; k < 4; k++) wc0[k] = packed[offP0[k] + t];

    // issue tile t+1 loads (in flight during this tile's compute)
    if (t + 1 < NT) {
      const char* gb = gbase + (size_t)(t + 1) * (CPT * 256);
      g0 = *(const uint4*)(gb);
      g1 = *(const uint4*)(gb + 16 * 256);
    }

    const unsigned char* buf = lds[t & 1];
    #pragma unroll
    for (int s = 0; s < 2; s++) {
      const bf16x8* bl = (const bf16x8*)(buf + (unsigned)(s * 16 + c) * LDS_COL + q * 16);
      bf16x8 b0 = bl[0], b1 = bl[4], b2 = bl[8], b3 = bl[12];

      f32x4 acc0 = {0, 0, 0, 0};
      acc0 = __builtin_amdgcn_mfma_f32_16x16x32_bf16(a0[0], b0, acc0, 0, 0, 0);
      acc0 = __builtin_amdgcn_mfma_f32_16x16x32_bf16(a0[1], b1, acc0, 0, 0, 0);
      acc0 = __builtin_amdgcn_mfma_f32_16x16x32_bf16(a0[2], b2, acc0, 0, 0, 0);
      acc0 = __builtin_amdgcn_mfma_f32_16x16x32_bf16(a0[3], b3, acc0, 0, 0, 0);

      int pos = s * 16 + c;   // bit position in the packed u32 word
      #pragma unroll
      for (int k = 0; k < 4; k++) {
        float e = __builtin_amdgcn_exp2f(acc0[k]);
        t0[k] += e;
        m0[k] = fmaf(e, (float)((wc0[k] >> pos) & 1u), m0[k]);
      }
    }

    // stage tile t+1 into the other buffer (waits on prefetch), one barrier
    if (t + 1 < NT) {
      unsigned char* nb = (unsigned char*)lds[(t + 1) & 1];
      *(uint4*)(nb + ldsoff)                = g0;
      *(uint4*)(nb + ldsoff + 16 * LDS_COL) = g1;
    }
    __syncthreads();
  }

  // Reduce across the 16 lanes (c) sharing each q group.
  #pragma unroll
  for (int sh = 1; sh < 16; sh <<= 1) {
    #pragma unroll
    for (int k = 0; k < 4; k++) {
      t0[k] += __shfl_xor(t0[k], sh);
      m0[k] += __shfl_xor(m0[k], sh);
    }
  }
  if (c == 0) {
    #pragma unroll
    for (int k = 0; k < 4; k++) {
      int r = rb + q * 4 + k;
      atomicAdd(&tot[r], t0[k]);
      atomicAdd(&msk[r], m0[k]);
    }
  }
}

// Kernel 3: loss = mean(log(p+tot') - log(p+msk')), diagonal subtracted here.
__global__ __launch_bounds__(256) void loss_kernel(
    const float* __restrict__ p, const float* __restrict__ tot,
    const float* __restrict__ msk, const float* __restrict__ eself,
    const float* __restrict__ mii, float* __restrict__ out)
{
  __shared__ float sd[4];
  int r = blockIdx.x * 256 + threadIdx.x;
  float pi = p[r];
  float es = eself[r];
  float t = tot[r] - es;                 // remove diagonal from total sum
  float m = msk[r] - es * mii[r];        // remove diagonal from masked sum
  float v = __builtin_amdgcn_logf(pi + t) - __builtin_amdgcn_logf(pi + m);
  float s = v * (1.0f / (LOG2E * (float)NROWS));
  #pragma unroll
  for (int sh = 1; sh < 64; sh <<= 1) s += __shfl_xor(s, sh);
  int wave = threadIdx.x >> 6, lane = threadIdx.x & 63;
  if (lane == 0) sd[wave] = s;
  __syncthreads();
  if (threadIdx.x == 0) atomicAdd(out, sd[0] + sd[1] + sd[2] + sd[3]);
}

extern "C" void kernel_launch(void* const* d_in, const int* in_sizes, int n_in,
                              void* d_out, int out_size, void* d_ws, size_t ws_size,
                              hipStream_t stream) {
  const float* x  = (const float*)d_in[0];   // inst_embed [N,D]
  const float* pr = (const float*)d_in[1];   // proxy [N,D]
  const float* nm = (const float*)d_in[2];   // negative_mask [100,N]
  const int*   lb = (const int*)d_in[3];     // labels [N]
  const float* tp = (const float*)d_in[4];   // temperature
  // margin (d_in[5]) cancels algebraically in numerator/denominator

  char* ws = (char*)d_ws;
  unsigned short* xnA = (unsigned short*)ws;                        // 2 MB
  unsigned short* xnB = xnA + (size_t)NROWS * DD;                   // 2 MB
  float* p     = (float*)(xnB + (size_t)NROWS * DD);
  float* tot   = p + NROWS;
  float* msk   = tot + NROWS;
  float* eself = msk + NROWS;
  float* miiv  = eself + NROWS;
  unsigned int* packed = (unsigned int*)(miiv + NROWS);             // 102.4 KB
  float* out = (float*)d_out;

  norm_kernel<<<NORM_BLOCKS + PACK_BLOCKS, 256, 0, stream>>>(
      x, pr, nm, lb, tp, xnA, xnB, p, eself, miiv, tot, msk, packed, out);
  main_kernel<<<dim3(NROWS / RPB, SPLIT), 256, 0, stream>>>(xnA, xnB, packed,
                                                            lb, tot, msk);
  loss_kernel<<<NROWS / 256, 256, 0, stream>>>(p, tot, msk, eself, miiv, out);
}